// Round 1
// baseline (201.610 us; speedup 1.0000x reference)
//
#include <hip/hip_runtime.h>
#include <cstddef>

#define B_   16
#define C_   256
#define HW_  4096

typedef __attribute__((ext_vector_type(8)))  short bf16x8;
typedef __attribute__((ext_vector_type(16))) float f32x16;

static __device__ __forceinline__ unsigned short f2bf(float f) {
    unsigned int u = __float_as_uint(f);
    u += 0x7fffu + ((u >> 16) & 1u);          // RNE
    return (unsigned short)(u >> 16);
}

// ---------------------------------------------------------------------------
// Kernel E: fused square + NCHW->NHWC bf16 + per-(b,q,h) energy argmax
// partials. grid = (b,h) = 1024 blocks x 256 thr. Stores go through an LDS
// transpose so global writes are 512B-contiguous per 32-lane group.
// ---------------------------------------------------------------------------
__global__ __launch_bounds__(256) void fused_energy(const float* __restrict__ x,
                                                    unsigned short* __restrict__ xsqN,
                                                    float* __restrict__ pval,
                                                    int* __restrict__ pidx) {
    int blk = blockIdx.x;
    int b = blk >> 6, h = blk & 63;
    int tid = threadIdx.x;
    int w = tid & 63, layer = tid >> 6;
    __shared__ float earr[4][4][64];
    __shared__ unsigned short tile[64][264];   // row stride 264 ush = 528B (16B-mult, bank-spread)
    float e0 = 0.f, e1 = 0.f, e2 = 0.f, e3 = 0.f;
    const float* xb = x + (size_t)b * C_ * HW_ + h * 64 + w;
#pragma unroll
    for (int i = 0; i < 8; ++i) {
        int c0 = (i * 4 + layer) * 8;
        union { unsigned short us[8]; int4 v; } u;
        float es = 0.f;
#pragma unroll
        for (int k = 0; k < 8; ++k) {
            float v = xb[(size_t)(c0 + k) * HW_];
            float s = v * v;
            es += s;
            u.us[k] = f2bf(s);
        }
        *(int4*)&tile[w][c0] = u.v;
        if ((i >> 1) == 0) e0 += es;
        else if ((i >> 1) == 1) e1 += es;
        else if ((i >> 1) == 2) e2 += es;
        else e3 += es;
    }
    earr[layer][0][w] = e0; earr[layer][1][w] = e1;
    earr[layer][2][w] = e2; earr[layer][3][w] = e3;
    __syncthreads();
    // contiguous NHWC stores: 32 lanes cover one 512B row segment
    size_t base = (size_t)(b * 64 + h) * 64 * 256;
#pragma unroll
    for (int it = 0; it < 8; ++it) {
        int row  = it * 8 + (tid >> 5);
        int col8 = (tid & 31) * 8;
        *(int4*)(xsqN + base + (size_t)row * 256 + col8) = *(int4*)&tile[row][col8];
    }
    int q = tid >> 6;
    float ev = earr[0][q][w] + earr[1][q][w] + earr[2][q][w] + earr[3][q][w];
    int ix = h * 64 + w;
#pragma unroll
    for (int off = 32; off; off >>= 1) {
        float ov = __shfl_down(ev, off);
        int   oi = __shfl_down(ix, off);
        if (ov > ev || (ov == ev && oi < ix)) { ev = ov; ix = oi; }
    }
    if ((tid & 63) == 0) {
        pval[(b * 64 + h) * 4 + q] = ev;
        pidx[(b * 64 + h) * 4 + q] = ix;
    }
}

// ---------------------------------------------------------------------------
// Final argmax over h per (b,q). grid = 64 blocks (b*4+q) x 64 thr.
// ---------------------------------------------------------------------------
__global__ __launch_bounds__(64) void energy_final(const float* __restrict__ pval,
                                                   const int* __restrict__ pidx,
                                                   int* __restrict__ lm) {
    int bq = blockIdx.x;
    int b = bq >> 2, q = bq & 3;
    int h = threadIdx.x;
    float ev = pval[(b * 64 + h) * 4 + q];
    int   ix = pidx[(b * 64 + h) * 4 + q];
#pragma unroll
    for (int off = 32; off; off >>= 1) {
        float ov = __shfl_down(ev, off);
        int   oi = __shfl_down(ix, off);
        if (ov > ev || (ov == ev && oi < ix)) { ev = ov; ix = oi; }
    }
    if (h == 0) lm[bq] = ix;
}

// ---------------------------------------------------------------------------
// Landmark value table Lval[b][c] (bf16). 16 blocks x 256 thr.
// ---------------------------------------------------------------------------
__global__ __launch_bounds__(256) void lval_kernel(const unsigned short* __restrict__ xsqN,
                                                   const int* __restrict__ lm,
                                                   unsigned short* __restrict__ Lval) {
    int t = blockIdx.x * 256 + threadIdx.x;   // b*256 + c
    int b = t >> 8, c = t & 255, q = c >> 6;
    int l = lm[b * 4 + q];
    Lval[t] = xsqN[((size_t)((b * 64 + (l >> 6)) * 64 + (l & 63))) * 256 + c];
}

// ---------------------------------------------------------------------------
// Weight pack -> fragment-ordered bf16 (unchanged, verified).
// Chunk (j,cib) = 16KB contiguous: offset (j*8+cib)*8192 ushorts.
// ---------------------------------------------------------------------------
__global__ __launch_bounds__(64) void wt_pack(const float* __restrict__ w,
                                              unsigned short* __restrict__ wa) {
    int blk  = blockIdx.x;
    int lane = threadIdx.x;
    int cog = blk & 7;
    int s   = (blk >> 3) & 1;
    int cib = (blk >> 4) & 7;
    int j   = blk >> 7;
    int co  = cog * 32 + (lane & 31);
    int k0  = cib * 32 + s * 16 + (lane >> 5) * 8;
    union { unsigned short us[8]; int4 v; } u;
#pragma unroll
    for (int jj = 0; jj < 8; ++jj) {
        int ci = k0 + jj;
        u.us[jj] = f2bf(w[(size_t)(co * 256 + ci) * 9 + j]);
    }
    *(int4*)(wa + ((size_t)blk * 64 + lane) * 8) = u.v;
}

// ---------------------------------------------------------------------------
// Conv: implicit-GEMM bf16 MFMA.
//   A (weights): loaded DIRECTLY global->VGPR in fragment order (wt_pack's
//     layout). Weights are 1.18 MB = L2-resident; the 4 wx-waves of a block
//     issue identical 1KB lines back-to-back so L1 absorbs the duplicates.
//     This removes the A LDS round-trip (64 of ~120 LDS instrs/phase) AND
//     the per-phase cross-wave hazard.
//   B (image tile): staged in LDS, double-buffered PER CIB. The only
//     cross-wave hazard is the cib-boundary buffer swap -> ONE __syncthreads
//     per cib (8 total) instead of 72. Waves free-run across the 9 taps.
// Block: 512 thr = 8 waves; tile 256co x 256px (4 rows). Wave: 128co x 64px.
// Grid 256 = 1 block/CU.
// ---------------------------------------------------------------------------
__global__ __launch_bounds__(512, 2) void conv_mfma(const unsigned short* __restrict__ xsqN,
                                                    const unsigned short* __restrict__ wa,
                                                    const float* __restrict__ bias,
                                                    const int* __restrict__ lm,
                                                    const unsigned short* __restrict__ Lval,
                                                    float* __restrict__ out) {
    int pt = blockIdx.x;              // b*16 + hq
    int b  = pt >> 4;
    int h0 = (pt & 15) * 4;
    int tid  = threadIdx.x;
    int lane = tid & 63;
    int wv   = tid >> 6;
    int wy = wv >> 2, wx = wv & 3;    // co half / image row
    int l31 = lane & 31, qh = lane >> 5;

    __shared__ unsigned short Bs[2][6 * 66 * 40];   // 63.4 KB (only LDS use now)

    f32x16 acc[4][2];
#pragma unroll
    for (int mt = 0; mt < 4; ++mt)
#pragma unroll
        for (int nt = 0; nt < 2; ++nt)
#pragma unroll
            for (int r = 0; r < 16; ++r) acc[mt][nt][r] = 0.f;

    int4 sv[4];   // B prefetch registers (live across one cib)

    // ---- prologue: stage B(cib=0) with rect-max into Bs[0]
    {
#pragma unroll
        for (int t2 = 0; t2 < 4; ++t2) {
            int idx = tid + t2 * 512;
            int4 v = {0, 0, 0, 0};
            if (idx < 1584) {
                int pr = idx / 264; int rem = idx - pr * 264;
                int pc = rem >> 2;  int part = rem & 3;
                int grow = h0 - 1 + pr, gcol = pc - 1;
                if ((unsigned)grow < 64u && (unsigned)gcol < 64u)
                    v = *(const int4*)(xsqN + (((size_t)(b * 64 + grow) * 64 + gcol) * 256 + part * 8));
            }
            sv[t2] = v;
        }
        int l = lm[b * 4 + 0];
        int hm = l >> 6, wm = l & 63;
#pragma unroll
        for (int t2 = 0; t2 < 4; ++t2) {
            int idx = tid + t2 * 512;
            if (idx < 1584) {
                int pr = idx / 264; int rem = idx - pr * 264;
                int pc = rem >> 2;  int part = rem & 3;
                int grow = h0 - 1 + pr, gcol = pc - 1;
                union { int4 v; unsigned short us[8]; } u; u.v = sv[t2];
                bool inb = ((unsigned)grow < 64u) && ((unsigned)gcol < 64u);
                if (inb && grow <= hm && gcol <= wm) {     // quadrant 0: h<=hm, w<=wm
                    union { int4 v; unsigned short us[8]; } Lu;
                    Lu.v = *(const int4*)(Lval + b * 256 + part * 8);
#pragma unroll
                    for (int k = 0; k < 8; ++k)
                        if (Lu.us[k] > u.us[k]) u.us[k] = Lu.us[k];
                }
                *(int4*)(&Bs[0][(pr * 66 + pc) * 40 + part * 8]) = u.v;
            }
        }
    }
    __syncthreads();

    // A fragment base for this wave (fragment units of 16B):
    //   frag[(j*8+cib)*1024 + (s*8 + wy*4 + m)*64 + lane]
    const bf16x8* Abase = (const bf16x8*)wa + (wy << 8) + lane;   // wy*4*64 + lane

    for (int cib = 0; cib < 8; ++cib) {
        // B global prefetch for cib+1 (register-staged, consumed after j-loop)
        if (cib < 7) {
            int nc = cib + 1;
#pragma unroll
            for (int t2 = 0; t2 < 4; ++t2) {
                int idx = tid + t2 * 512;
                int4 v = {0, 0, 0, 0};
                if (idx < 1584) {
                    int pr = idx / 264; int rem = idx - pr * 264;
                    int pc = rem >> 2;  int part = rem & 3;
                    int grow = h0 - 1 + pr, gcol = pc - 1;
                    if ((unsigned)grow < 64u && (unsigned)gcol < 64u)
                        v = *(const int4*)(xsqN + (((size_t)(b * 64 + grow) * 64 + gcol) * 256 + nc * 32 + part * 8));
                }
                sv[t2] = v;
            }
        }

        const bf16x8* Ac = Abase + ((size_t)cib << 10);
        const unsigned short* Bb = &Bs[cib & 1][0];

        // ---- 9 taps, NO barriers: waves free-run within the cib ----
        for (int j = 0; j < 9; ++j) {
            const bf16x8* Ag = Ac + (size_t)j * 8192;
            // 8 A fragments direct from global (L1/L2-hit, coalesced 1KB each)
            bf16x8 a00 = Ag[0];
            bf16x8 a01 = Ag[64];
            bf16x8 a02 = Ag[128];
            bf16x8 a03 = Ag[192];
            bf16x8 a10 = Ag[512];
            bf16x8 a11 = Ag[576];
            bf16x8 a12 = Ag[640];
            bf16x8 a13 = Ag[704];

            int j3 = j / 3;
            int dh = j3 - 1, dw = (j - j3 * 3) - 1;
            int r  = wx + dh + 1;
            int w0 = l31 + dw + 1;
            const unsigned short* Bp = Bb + (r * 66 + w0) * 40 + qh * 8;
            bf16x8 b00 = *(const bf16x8*)(Bp);
            bf16x8 b01 = *(const bf16x8*)(Bp + 1280);   // +32 pixels
            bf16x8 b10 = *(const bf16x8*)(Bp + 16);     // s=1
            bf16x8 b11 = *(const bf16x8*)(Bp + 1296);

            __builtin_amdgcn_s_setprio(1);
            acc[0][0] = __builtin_amdgcn_mfma_f32_32x32x16_bf16(a00, b00, acc[0][0], 0, 0, 0);
            acc[0][1] = __builtin_amdgcn_mfma_f32_32x32x16_bf16(a00, b01, acc[0][1], 0, 0, 0);
            acc[1][0] = __builtin_amdgcn_mfma_f32_32x32x16_bf16(a01, b00, acc[1][0], 0, 0, 0);
            acc[1][1] = __builtin_amdgcn_mfma_f32_32x32x16_bf16(a01, b01, acc[1][1], 0, 0, 0);
            acc[2][0] = __builtin_amdgcn_mfma_f32_32x32x16_bf16(a02, b00, acc[2][0], 0, 0, 0);
            acc[2][1] = __builtin_amdgcn_mfma_f32_32x32x16_bf16(a02, b01, acc[2][1], 0, 0, 0);
            acc[3][0] = __builtin_amdgcn_mfma_f32_32x32x16_bf16(a03, b00, acc[3][0], 0, 0, 0);
            acc[3][1] = __builtin_amdgcn_mfma_f32_32x32x16_bf16(a03, b01, acc[3][1], 0, 0, 0);
            acc[0][0] = __builtin_amdgcn_mfma_f32_32x32x16_bf16(a10, b10, acc[0][0], 0, 0, 0);
            acc[0][1] = __builtin_amdgcn_mfma_f32_32x32x16_bf16(a10, b11, acc[0][1], 0, 0, 0);
            acc[1][0] = __builtin_amdgcn_mfma_f32_32x32x16_bf16(a11, b10, acc[1][0], 0, 0, 0);
            acc[1][1] = __builtin_amdgcn_mfma_f32_32x32x16_bf16(a11, b11, acc[1][1], 0, 0, 0);
            acc[2][0] = __builtin_amdgcn_mfma_f32_32x32x16_bf16(a12, b10, acc[2][0], 0, 0, 0);
            acc[2][1] = __builtin_amdgcn_mfma_f32_32x32x16_bf16(a12, b11, acc[2][1], 0, 0, 0);
            acc[3][0] = __builtin_amdgcn_mfma_f32_32x32x16_bf16(a13, b10, acc[3][0], 0, 0, 0);
            acc[3][1] = __builtin_amdgcn_mfma_f32_32x32x16_bf16(a13, b11, acc[3][1], 0, 0, 0);
            __builtin_amdgcn_s_setprio(0);
        }

        // ---- B rect-max + store for cib+1 (into other buffer), then the
        //      ONE barrier of this cib: publishes writes AND retires reads.
        if (cib < 7) {
            int nc = cib + 1;
            int l = lm[b * 4 + (nc >> 1)];
            int hm = l >> 6, wm = l & 63;
            bool qhle = (nc >> 1) < 2;
            bool qwle = ((nc >> 1) & 1) == 0;
            unsigned short* Bw = &Bs[(cib + 1) & 1][0];
#pragma unroll
            for (int t2 = 0; t2 < 4; ++t2) {
                int idx = tid + t2 * 512;
                if (idx < 1584) {
                    int pr = idx / 264; int rem = idx - pr * 264;
                    int pc = rem >> 2;  int part = rem & 3;
                    int grow = h0 - 1 + pr, gcol = pc - 1;
                    union { int4 v; unsigned short us[8]; } u; u.v = sv[t2];
                    bool inb = ((unsigned)grow < 64u) && ((unsigned)gcol < 64u);
                    bool hok = qhle ? (grow <= hm) : (grow >= hm);
                    bool wok = qwle ? (gcol <= wm) : (gcol >= wm);
                    if (inb && hok && wok) {
                        union { int4 v; unsigned short us[8]; } Lu;
                        Lu.v = *(const int4*)(Lval + b * 256 + nc * 32 + part * 8);
#pragma unroll
                        for (int k = 0; k < 8; ++k)
                            if (Lu.us[k] > u.us[k]) u.us[k] = Lu.us[k];
                    }
                    *(int4*)(&Bw[(pr * 66 + pc) * 40 + part * 8]) = u.v;
                }
            }
        }
        __syncthreads();
    }

    // ---- epilogue ----
    int h = h0 + wx;
#pragma unroll
    for (int mt = 0; mt < 4; ++mt) {
#pragma unroll
        for (int nt = 0; nt < 2; ++nt) {
#pragma unroll
            for (int r = 0; r < 16; ++r) {
                int row = (r & 3) + 8 * (r >> 2) + 4 * qh;
                int co  = wy * 128 + mt * 32 + row;
                int w   = nt * 32 + l31;
                out[(((size_t)(b * 256 + co)) * 64 + h) * 64 + w] = acc[mt][nt][r] + bias[co];
            }
        }
    }
}

// ---------------------------------------------------------------------------
extern "C" void kernel_launch(void* const* d_in, const int* in_sizes, int n_in,
                              void* d_out, int out_size, void* d_ws, size_t ws_size,
                              hipStream_t stream) {
    const float* x      = (const float*)d_in[0];
    const float* weight = (const float*)d_in[1];
    const float* bias   = (const float*)d_in[2];
    float* out = (float*)d_out;

    char* ws = (char*)d_ws;
    int*            lmp  = (int*)ws;                         // 64 ints @0
    float*          pval = (float*)(ws + 256);               // 4096 f
    int*            pidx = (int*)(ws + 256 + 16384);         // 4096 i
    unsigned short* Lval = (unsigned short*)(ws + 256 + 32768);  // 4096 ush
    unsigned short* Wa   = (unsigned short*)(ws + 49152);    // 1.18 MB
    unsigned short* xsqN = (unsigned short*)(ws + 49152 + 1179648); // NHWC bf16 33.55 MB

    hipLaunchKernelGGL(fused_energy, dim3(1024), dim3(256), 0, stream, x, xsqN, pval, pidx);
    hipLaunchKernelGGL(energy_final, dim3(64), dim3(64), 0, stream, pval, pidx, lmp);
    hipLaunchKernelGGL(lval_kernel, dim3(16), dim3(256), 0, stream, xsqN, lmp, Lval);
    hipLaunchKernelGGL(wt_pack, dim3(1152), dim3(64), 0, stream, weight, Wa);
    hipLaunchKernelGGL(conv_mfma, dim3(256), dim3(512), 0, stream, xsqN, Wa, bias, lmp, Lval, out);
}